// Round 5
// baseline (206.739 us; speedup 1.0000x reference)
//
#include <hip/hip_runtime.h>
#include <hip/hip_bf16.h>
#include <math.h>

typedef __hip_bfloat16 bf16;
typedef __attribute__((ext_vector_type(8))) short short8;
typedef __attribute__((ext_vector_type(16))) float floatx16;

// Problem constants
constexpr int B_   = 2;
constexpr int T_   = 8;
constexpr int HW   = 48 * 48;          // 2304
constexpr int S_   = T_ * HW;          // 18432
constexpr int D_   = 64;
constexpr int NH   = 4;
constexpr int DH   = 16;
constexpr int M_   = 32;
constexpr int BS   = B_ * S_;          // 36864 tokens
constexpr int BSD  = BS * D_;          // 2359296
constexpr int BH   = B_ * NH;          // 8 sequences
constexpr int BHS  = BH * S_;          // 147456 rows
constexpr int CHUNK = 32;
constexpr int NC   = S_ / CHUNK;       // 576 chunks per sequence
constexpr int STATE = M_ * DH + M_;    // 544 floats of scan state
constexpr int GSLOTS = 64;             // gmax atomic slots
constexpr int GSTRIDE = 32;            // floats between slots (128 B = own cache line)
constexpr int SCB = 16;                // scan: state-elems per block
constexpr int SRG = 16;                // scan: runs per (bh, c)
constexpr int SRUN = NC / SRG;         // 36 chunks per run
constexpr float DN = 0.5f;                         // 16^-0.25
constexpr float RATIO = 0.17677669529663687f;      // 32^-0.5

__device__ __forceinline__ unsigned short f2bf(float f) {
  bf16 h = __float2bfloat16(f);
  return *reinterpret_cast<unsigned short*>(&h);
}
__device__ __forceinline__ float bf2f(bf16 v) { return __bfloat162float(v); }
__device__ __forceinline__ float bfs2f(short s) {
  return __uint_as_float(((unsigned)(unsigned short)s) << 16);
}
__device__ __forceinline__ void atomicMaxFloat(float* addr, float val) {
  if (val >= 0.f) atomicMax((int*)addr, __float_as_int(val));
  else atomicMin((unsigned int*)addr, __float_as_uint(val));
}

// ---- prep: bf16 weight conversion (transposed so MFMA B-frags are contiguous short8)
// ---- + gmax slot init. Bitwise-identical values to per-kernel f2bf conversion.
__global__ void __launch_bounds__(256) k_prep(const float* __restrict__ wq,
        const float* __restrict__ wk, const float* __restrict__ wv,
        const float* __restrict__ wo, const float* __restrict__ w1,
        const float* __restrict__ proj,
        short* __restrict__ wqT, short* __restrict__ wkT, short* __restrict__ wvT,
        short* __restrict__ woT, short* __restrict__ w1T, short* __restrict__ projb,
        float* __restrict__ gmax) {
  int tid = blockIdx.x * 256 + threadIdx.x;      // 64 blocks x 256 = 16384
  if (tid < GSLOTS) ((unsigned*)gmax)[tid * GSTRIDE] = 0xff800000u;   // -inf seed
  if (tid < 512) projb[tid] = (short)f2bf(proj[tid]);                 // [32][16] row-major
  if (tid < 4096) {
    int c = tid >> 6, r = tid & 63;              // T[c][r] = w[r][c]
    wqT[tid] = (short)f2bf(wq[r * 64 + c]);
    wkT[tid] = (short)f2bf(wk[r * 64 + c]);
    wvT[tid] = (short)f2bf(wv[r * 64 + c]);
    woT[tid] = (short)f2bf(wo[r * 64 + c]);
  }
  {
    int c = tid >> 6, r = tid & 63;              // w1: [64][256] -> T[256][64]
    w1T[tid] = (short)f2bf(w1[r * 256 + c]);
  }
}

// ---- fused: conv3d(1x1x1)+softplus+LN1 (LDS) + QKV MFMA + k-dash global max (C-lite).
// ---- h never hits HBM; q,k stored PRE-SCALED by DN (exact exponent shift).
__global__ void __launch_bounds__(256) k_preqkv(const float* __restrict__ x,
                      const float* __restrict__ pw, const float* __restrict__ pb,
                      const float* __restrict__ g, const float* __restrict__ bb,
                      const short* __restrict__ wqT, const short* __restrict__ wkT,
                      const short* __restrict__ wvT, const short* __restrict__ projb,
                      bf16* __restrict__ tok, bf16* __restrict__ q,
                      bf16* __restrict__ k, bf16* __restrict__ v,
                      float* __restrict__ gmax) {
  __shared__ __align__(16) short sh[32 * 64];     // LN1 out, XOR-swizzled 16B chunks
  __shared__ __align__(16) short sk[32 * 64];     // (k*DN) bf16, [token][d], byte-swizzled
  int tid = threadIdx.x;
  int tbase = blockIdx.x * 32;

  // ---- phase A: 32 tokens x 64 channels; each thread owns 8 consecutive values
  {
    size_t f0 = (size_t)tbase * 64;
    int b = (int)(f0 / ((size_t)D_ * S_));
    int rem = (int)(f0 % ((size_t)D_ * S_));
    int d = rem / S_;                    // whole block lies in one (b,d) plane
    int pos0 = rem % S_;
    float w0 = pw[d * 3 + 0], w1 = pw[d * 3 + 1], w2 = pw[d * 3 + 2], pbd = pb[d];
    const float* xb = x + ((size_t)b * 3) * S_ + pos0 + tid * 8;
    float4 x0a = *(const float4*)(xb);
    float4 x0b = *(const float4*)(xb + 4);
    float4 x1a = *(const float4*)(xb + S_);
    float4 x1b = *(const float4*)(xb + S_ + 4);
    float4 x2a = *(const float4*)(xb + 2 * S_);
    float4 x2b = *(const float4*)(xb + 2 * S_ + 4);
    float xf0[8] = {x0a.x, x0a.y, x0a.z, x0a.w, x0b.x, x0b.y, x0b.z, x0b.w};
    float xf1[8] = {x1a.x, x1a.y, x1a.z, x1a.w, x1b.x, x1b.y, x1b.z, x1b.w};
    float xf2[8] = {x2a.x, x2a.y, x2a.z, x2a.w, x2b.x, x2b.y, x2b.z, x2b.w};
    float t[8];
    short8 tv;
#pragma unroll
    for (int j = 0; j < 8; ++j) {
      float a = xf0[j] * w0 + xf1[j] * w1 + xf2[j] * w2 + pbd;
      t[j] = fmaxf(a, 0.f) + log1pf(expf(-fabsf(a)));   // softplus
      tv[j] = (short)f2bf(t[j]);
    }
    *(short8*)(tok + f0 + (size_t)tid * 8) = tv;
    float s1 = 0.f, s2 = 0.f;
#pragma unroll
    for (int j = 0; j < 8; ++j) { s1 += t[j]; s2 += t[j] * t[j]; }
#pragma unroll
    for (int off = 4; off; off >>= 1) {       // LN reduce over 8 lanes = 64 channels
      s1 += __shfl_xor(s1, off, 8);
      s2 += __shfl_xor(s2, off, 8);
    }
    float mu = s1 * (1.f / 64.f);
    float var = s2 * (1.f / 64.f) - mu * mu;
    float rs = rsqrtf(var + 1e-5f);
    int tt = tid >> 3, j8 = tid & 7;
    short8 hv;
#pragma unroll
    for (int j = 0; j < 8; ++j) {
      int c = j8 * 8 + j;
      hv[j] = (short)f2bf((t[j] - mu) * rs * g[c] + bb[c]);
    }
    *(short8*)&sh[tt * 64 + ((j8 ^ (tt & 7)) * 8)] = hv;   // XOR-swizzled 16B chunk
  }
  __syncthreads();

  int w = tid >> 6;
  int L = tid & 63;
  int half = L >> 5;
  int n = L & 31;

  // ---- phase B: waves {0,1,2} = {q,k,v} MFMA; bf16 transposed weights, short8 frags
  if (w < 3) {
    const short* wmT = (w == 0) ? wqT : (w == 1) ? wkT : wvT;
    bf16* outm = (w == 0) ? q : (w == 1) ? k : v;

    short8 a[4];
#pragma unroll
    for (int c = 0; c < 4; ++c)
      a[c] = *(const short8*)&sh[n * 64 + (((c * 2 + half) ^ (n & 7)) * 8)];
#pragma unroll
    for (int ct = 0; ct < 2; ++ct) {
      int col = ct * 32 + n;
      short8 bfrag[4];
#pragma unroll
      for (int c = 0; c < 4; ++c)
        bfrag[c] = *(const short8*)&wmT[col * 64 + c * 16 + half * 8];
      floatx16 acc;
#pragma unroll
      for (int i = 0; i < 16; ++i) acc[i] = 0.f;
      acc = __builtin_amdgcn_mfma_f32_32x32x16_bf16(a[0], bfrag[0], acc, 0, 0, 0);
      acc = __builtin_amdgcn_mfma_f32_32x32x16_bf16(a[1], bfrag[1], acc, 0, 0, 0);
      acc = __builtin_amdgcn_mfma_f32_32x32x16_bf16(a[2], bfrag[2], acc, 0, 0, 0);
      acc = __builtin_amdgcn_mfma_f32_32x32x16_bf16(a[3], bfrag[3], acc, 0, 0, 0);
      int head = col >> 4, di = col & 15;
#pragma unroll
      for (int r = 0; r < 16; ++r) {
        int row = (r & 3) + 8 * (r >> 2) + 4 * half;
        int token = tbase + row;
        int b = token / S_, s = token % S_;
        unsigned short us = f2bf(acc[r]);
        if (w == 2) {
          outm[((size_t)(b * NH + head) * S_ + s) * DH + di] = *(bf16*)&us;
        } else {
          unsigned short usd = f2bf(bfs2f((short)us) * DN);   // exact x0.5 round-trip
          outm[((size_t)(b * NH + head) * S_ + s) * DH + di] = *(bf16*)&usd;
          if (w == 1)
            *(short*)((char*)sk + row * 128 + ((col * 2) ^ ((row & 7) << 4))) = (short)usd;
        }
      }
    }
  }
  __syncthreads();

  // ---- phase C-lite: wave w = head w. One Pk MFMA, raw-dash max, spread atomic.
  {
    short8 ak;
    short8 bp = *(const short8*)&projb[n * 16 + half * 8];    // B[d][m=n]
    int roff = n * 128 + ((w * 32 + half * 16) ^ ((n & 7) << 4));
    ak = *(const short8*)((const char*)sk + roff);
    floatx16 Pk;
#pragma unroll
    for (int i = 0; i < 16; ++i) Pk[i] = 0.f;
    Pk = __builtin_amdgcn_mfma_f32_32x32x16_bf16(ak, bp, Pk, 0, 0, 0);
    float bmax = -3.4e38f;
#pragma unroll
    for (int r = 0; r < 16; ++r) bmax = fmaxf(bmax, Pk[r]);
    for (int off = 32; off; off >>= 1) bmax = fmaxf(bmax, __shfl_xor(bmax, off));
    if (L == 0)
      atomicMaxFloat(&gmax[((blockIdx.x * 4 + w) & (GSLOTS - 1)) * GSTRIDE], bmax);
  }
}

// ---- one dispatch, two independent block-ranges running CONCURRENTLY:
// ----   blk < BH*NC          : csfin (kp finalize + per-chunk sums)
// ----   blk >= BH*NC (1152)  : feat  (qp feature map, reads q only)
// ---- q,k arrive PRE-SCALED by DN.
__global__ void __launch_bounds__(256) k_featcsfin(const float* __restrict__ gmax,
                      const bf16* __restrict__ q, const bf16* __restrict__ k,
                      const bf16* __restrict__ v, const short* __restrict__ projb,
                      bf16* __restrict__ qpb, bf16* __restrict__ kpb,
                      float* __restrict__ ckv) {
  __shared__ __align__(16) float sKp[CHUNK * 32];
  __shared__ __align__(16) float sVc[CHUNK * 16];
  int tid = threadIdx.x;
  int w = tid >> 6, L = tid & 63, half = L >> 5, n = L & 31;
  short8 bp = *(const short8*)&projb[n * 16 + half * 8];     // B[d][m=n]

  if (blockIdx.x >= BH * NC) {
    // ---------------- feat: qp bf16 out; 128 rows per block ----------------
    int fblk = blockIdx.x - BH * NC;
    int rowbase = fblk * 128 + w * 32;
    short8 aq = *(const short8*)(q + (size_t)(rowbase + n) * 16 + half * 8);
    float dq = 0.f;
#pragma unroll
    for (int j = 0; j < 8; ++j) { float f = bfs2f(aq[j]); dq += f * f; }
    dq += __shfl_xor(dq, 32);
    dq *= 0.5f;
    floatx16 Pq;
#pragma unroll
    for (int i = 0; i < 16; ++i) Pq[i] = 0.f;
    Pq = __builtin_amdgcn_mfma_f32_32x32x16_bf16(aq, bp, Pq, 0, 0, 0);
#pragma unroll
    for (int r = 0; r < 16; ++r) {
      int i = (r & 3) + 8 * (r >> 2) + 4 * half;
      float mx = Pq[r];
      for (int off = 16; off; off >>= 1) mx = fmaxf(mx, __shfl_xor(mx, off, 32));
      float dqi = __shfl(dq, i, 64);          // row i's dq lives on lane i (<32)
      float val = RATIO * (expf(Pq[r] - dqi - mx) + 1e-4f);
      qpb[(size_t)(rowbase + i) * 32 + n] = __float2bfloat16(val);
    }
    return;
  }

  // ---------------- csfin ----------------
  int blk = blockIdx.x;
  int bh = blk / NC, c = blk % NC;
  int base = bh * S_ + c * CHUNK;
  if (w == 0) {
    float gm = gmax[L * GSTRIDE];             // 64 slots -> wave-reduce max
    for (int off = 32; off; off >>= 1) gm = fmaxf(gm, __shfl_xor(gm, off));
    short8 ak = *(const short8*)(k + (size_t)(base + n) * 16 + half * 8);
    float dk = 0.f;
#pragma unroll
    for (int j = 0; j < 8; ++j) { float f = bfs2f(ak[j]); dk += f * f; }
    dk += __shfl_xor(dk, 32);
    dk *= 0.5f;
    floatx16 Pk;
#pragma unroll
    for (int i = 0; i < 16; ++i) Pk[i] = 0.f;
    Pk = __builtin_amdgcn_mfma_f32_32x32x16_bf16(ak, bp, Pk, 0, 0, 0);
#pragma unroll
    for (int r = 0; r < 16; ++r) {
      int i = (r & 3) + 8 * (r >> 2) + 4 * half;
      float dgi = __shfl(dk, i, 64);
      sKp[i * 32 + n] = RATIO * (expf(Pk[r] - dgi - gm) + 1e-4f);
    }
  } else if (w == 1) {                       // stage V: 32 rows x 16 ch
    int row = L >> 1, h8 = (L & 1) * 8;
    short8 vs = *(const short8*)(v + (size_t)(base + row) * 16 + h8);
#pragma unroll
    for (int j = 0; j < 8; ++j) sVc[row * 16 + h8 + j] = bfs2f(vs[j]);
  }
  __syncthreads();
  {                                          // packed bf16 kpb store, coalesced
    int row = tid >> 3, m4 = tid & 7;
    float4 fin = *(const float4*)&sKp[row * 32 + m4 * 4];
    uint2 u;
    u.x = (unsigned)f2bf(fin.x) | ((unsigned)f2bf(fin.y) << 16);
    u.y = (unsigned)f2bf(fin.z) | ((unsigned)f2bf(fin.w) << 16);
    *(uint2*)&kpb[(size_t)(base + row) * 32 + m4 * 4] = u;
  }
  int m0 = tid >> 4, d0 = tid & 15;
  int m1 = m0 + 16;
  float a0 = 0.f, a1 = 0.f, az0 = 0.f, az1 = 0.f;
  for (int t = 0; t < CHUNK; ++t) {
    float k0 = sKp[t * 32 + m0];
    float k1 = sKp[t * 32 + m1];
    float vv = sVc[t * 16 + d0];
    a0 += k0 * vv;
    a1 += k1 * vv;
    if (d0 == 0) { az0 += k0; az1 += k1; }
  }
  float* outp = ckv + (size_t)blk * STATE;
  outp[m0 * 16 + d0] = a0;
  outp[m1 * 16 + d0] = a1;
  if (d0 == 0) { outp[512 + m0] = az0; outp[512 + m1] = az1; }
}

// ---- single-kernel segmented exclusive scan: 16 runs of 36 chunks, LDS run-prefix ----
__global__ void __launch_bounds__(256) k_scan(float* __restrict__ ckv) {
  __shared__ float sS[SRG][SCB];
  int blk = blockIdx.x;                      // BH * (STATE/SCB) = 8*34 = 272
  int bh = blk / (STATE / SCB);
  int c0 = (blk % (STATE / SCB)) * SCB;
  int cl = threadIdx.x & (SCB - 1);
  int rg = threadIdx.x >> 4;
  int c = c0 + cl;
  size_t base = ((size_t)bh * NC + rg * SRUN) * STATE + c;
  float s = 0.f;
#pragma unroll 6
  for (int i = 0; i < SRUN; ++i) s += ckv[base + (size_t)i * STATE];
  sS[rg][cl] = s;
  __syncthreads();
  float run = 0.f;
  for (int r = 0; r < rg; ++r) run += sS[r][cl];
  for (int i0 = 0; i0 < SRUN; i0 += 6) {
    float tb[6];
#pragma unroll
    for (int j = 0; j < 6; ++j) tb[j] = ckv[base + (size_t)(i0 + j) * STATE];
#pragma unroll
    for (int j = 0; j < 6; ++j) {
      ckv[base + (size_t)(i0 + j) * STATE] = run;
      run += tb[j];
    }
  }
}

// ---------------- within-chunk causal attention via MFMA (CHUNK=32; 4 chunks/block) ----------------
__global__ void __launch_bounds__(256) k_attn(const bf16* __restrict__ qpb,
                                              const bf16* __restrict__ kpb,
                                              const bf16* __restrict__ v,
                                              const float* __restrict__ ckv,
                                              bf16* __restrict__ attn) {
  __shared__ __align__(16) float sP[4][32 * 33 + 4];
  int tid = threadIdx.x;
  int w = tid >> 6;                 // wave -> chunk
  int L = tid & 63;
  int half = L >> 5;
  int n = L & 31;
  int chunk = blockIdx.x * 4 + w;
  int bh = chunk / NC, c = chunk % NC;
  int base = bh * S_ + c * CHUNK;

  short8 a1 = *(const short8*)(qpb + (size_t)(base + n) * 32 + half * 8);
  short8 a2 = *(const short8*)(qpb + (size_t)(base + n) * 32 + 16 + half * 8);
  short8 b1 = *(const short8*)(kpb + (size_t)(base + n) * 32 + half * 8);
  short8 b2 = *(const short8*)(kpb + (size_t)(base + n) * 32 + 16 + half * 8);

  floatx16 P;
#pragma unroll
  for (int i = 0; i < 16; ++i) P[i] = 0.f;
  P = __builtin_amdgcn_mfma_f32_32x32x16_bf16(a1, b1, P, 0, 0, 0);
  P = __builtin_amdgcn_mfma_f32_32x32x16_bf16(a2, b2, P, 0, 0, 0);

  float* sp = &sP[w][0];
#pragma unroll
  for (int r = 0; r < 16; ++r) {
    int i = (r & 3) + 8 * (r >> 2) + 4 * half;
    sp[i * 33 + n] = (n <= i) ? P[r] : 0.f;
  }
  __syncthreads();
  short8 pa1, pa2;
#pragma unroll
  for (int j = 0; j < 8; ++j) {
    pa1[j] = (short)f2bf(sp[n * 33 + half * 8 + j]);
    pa2[j] = (short)f2bf(sp[n * 33 + 16 + half * 8 + j]);
  }

  const float* cs = ckv + (size_t)chunk * STATE;
  const unsigned short one_bf = f2bf(1.f);
  short8 vb1, vb2, sb1, sb2;
#pragma unroll
  for (int j = 0; j < 8; ++j) {
    int t1 = half * 8 + j, t2 = 16 + half * 8 + j;
    vb1[j] = (n < 16) ? *(const short*)(v + (size_t)(base + t1) * 16 + n)
                      : (short)(n == 16 ? one_bf : 0);
    vb2[j] = (n < 16) ? *(const short*)(v + (size_t)(base + t2) * 16 + n)
                      : (short)(n == 16 ? one_bf : 0);
    float y1 = (n < 16) ? cs[t1 * 16 + n] : (n == 16 ? cs[512 + t1] : 0.f);
    float y2 = (n < 16) ? cs[t2 * 16 + n] : (n == 16 ? cs[512 + t2] : 0.f);
    sb1[j] = (short)f2bf(y1);
    sb2[j] = (short)f2bf(y2);
  }

  floatx16 O;
#pragma unroll
  for (int i = 0; i < 16; ++i) O[i] = 0.f;
  O = __builtin_amdgcn_mfma_f32_32x32x16_bf16(pa1, vb1, O, 0, 0, 0);
  O = __builtin_amdgcn_mfma_f32_32x32x16_bf16(pa2, vb2, O, 0, 0, 0);
  O = __builtin_amdgcn_mfma_f32_32x32x16_bf16(a1, sb1, O, 0, 0, 0);
  O = __builtin_amdgcn_mfma_f32_32x32x16_bf16(a2, sb2, O, 0, 0, 0);

  int srcl = 16 + 32 * half;
  float res[16];
#pragma unroll
  for (int r = 0; r < 16; ++r) {
    float den = __shfl(O[r], srcl, 64);
    res[r] = O[r] / den;
  }
  if (n < 16) {
    int b = bh >> 2, head = bh & 3;
#pragma unroll
    for (int r = 0; r < 16; ++r) {
      int i = (r & 3) + 8 * (r >> 2) + 4 * half;
      attn[((size_t)(b * S_ + c * CHUNK + i)) * 64 + head * 16 + n] = __float2bfloat16(res[r]);
    }
  }
}

// ---------------- attn(bf16) @ wo + bo + residual(bf16) + LayerNorm2; tok2 bf16, h2 bf16 ----------
__global__ void __launch_bounds__(128) k_wo_ln(const bf16* __restrict__ attn,
                        const short* __restrict__ woT, const float* __restrict__ bo,
                        const bf16* __restrict__ tok, const float* __restrict__ g,
                        const float* __restrict__ bb,
                        bf16* __restrict__ tok2, bf16* __restrict__ h2) {
  __shared__ __align__(16) float sC[32 * 68];
  int tid = threadIdx.x;
  int w = tid >> 6;                 // coltile
  int L = tid & 63;
  int half = L >> 5;
  int n = L & 31;
  int tbase = blockIdx.x * 32;

  short8 a[4];
  {
    const bf16* arow = attn + (size_t)(tbase + n) * 64 + half * 8;
#pragma unroll
    for (int c = 0; c < 4; ++c) a[c] = *(const short8*)(arow + c * 16);
  }
  int col = w * 32 + n;
  short8 bfrag[4];
#pragma unroll
  for (int c = 0; c < 4; ++c)
    bfrag[c] = *(const short8*)&woT[col * 64 + c * 16 + half * 8];
  floatx16 acc;
#pragma unroll
  for (int i = 0; i < 16; ++i) acc[i] = 0.f;
  acc = __builtin_amdgcn_mfma_f32_32x32x16_bf16(a[0], bfrag[0], acc, 0, 0, 0);
  acc = __builtin_amdgcn_mfma_f32_32x32x16_bf16(a[1], bfrag[1], acc, 0, 0, 0);
  acc = __builtin_amdgcn_mfma_f32_32x32x16_bf16(a[2], bfrag[2], acc, 0, 0, 0);
  acc = __builtin_amdgcn_mfma_f32_32x32x16_bf16(a[3], bfrag[3], acc, 0, 0, 0);
  float bias = bo[col];
#pragma unroll
  for (int r = 0; r < 16; ++r) {
    int row = (r & 3) + 8 * (r >> 2) + 4 * half;
    sC[row * 68 + col] = acc[r] + bf2f(tok[(size_t)(tbase + row) * 64 + col]) + bias;
  }
  __syncthreads();
  int tg = tid >> 5, cg = tid & 31;
  int c0 = cg * 2, c1 = c0 + 1;
  float g0 = g[c0], g1 = g[c1], be0 = bb[c0], be1 = bb[c1];
#pragma unroll
  for (int i = 0; i < 8; ++i) {
    int lrow = tg * 8 + i;
    int token = tbase + lrow;
    float t0 = sC[lrow * 68 + c0];
    float t1 = sC[lrow * 68 + c1];
    float s1 = t0 + t1, s2 = t0 * t0 + t1 * t1;
    for (int off = 16; off; off >>= 1) {
      s1 += __shfl_xor(s1, off, 32);
      s2 += __shfl_xor(s2, off, 32);
    }
    float mu = s1 * (1.f / 64.f);
    float var = s2 * (1.f / 64.f) - mu * mu;
    float rs = rsqrtf(var + 1e-5f);
    tok2[token * 64 + c0] = __float2bfloat16(t0);
    tok2[token * 64 + c1] = __float2bfloat16(t1);
    h2[token * 64 + c0] = __float2bfloat16((t0 - mu) * rs * g0 + be0);
    h2[token * 64 + c1] = __float2bfloat16((t1 - mu) * rs * g1 + be1);
  }
}

// ---------------- FF1 + Gavg fused via MFMA (h2 bf16 in, bf16 transposed w1) ----------------
__global__ void __launch_bounds__(256) k_ffg(const bf16* __restrict__ h2,
                                             const short* __restrict__ w1T,
                                             const float* __restrict__ b1,
                                             float* __restrict__ Gavg) {
  int tid = threadIdx.x;
  int w = tid >> 6;
  int L = tid & 63;
  int half = L >> 5;
  int n = L & 31;
  int blk = blockIdx.x;                 // B*64*9 = 1152
  int b = blk / 576;
  int rem = blk % 576;
  int ch = rem / 9;
  int jp0 = (rem % 9) * 4;
  int token_n = b * 18432 + ch * 288 + (n & 7) * 36 + jp0 + (n >> 3);

  short8 a[4];
  {
    const bf16* hrow = h2 + (size_t)token_n * 64 + half * 8;
#pragma unroll
    for (int c = 0; c < 4; ++c) a[c] = *(const short8*)(hrow + c * 16);
  }
  size_t gbase = ((size_t)(b * 64 + ch) * 36 + jp0);
#pragma unroll
  for (int ct = 0; ct < 2; ++ct) {
    int col = w * 64 + ct * 32 + n;
    short8 bfrag[4];
#pragma unroll
    for (int c = 0; c < 4; ++c)
      bfrag[c] = *(const short8*)&w1T[col * 64 + c * 16 + half * 8];
    floatx16 acc;
#pragma unroll
    for (int i = 0; i < 16; ++i) acc[i] = 0.f;
    acc = __builtin_amdgcn_mfma_f32_32x32x16_bf16(a[0], bfrag[0], acc, 0, 0, 0);
    acc = __builtin_amdgcn_mfma_f32_32x32x16_bf16(a[1], bfrag[1], acc, 0, 0, 0);
    acc = __builtin_amdgcn_mfma_f32_32x32x16_bf16(a[2], bfrag[2], acc, 0, 0, 0);
    acc = __builtin_amdgcn_mfma_f32_32x32x16_bf16(a[3], bfrag[3], acc, 0, 0, 0);
    float bias = b1[col];
#pragma unroll
    for (int j = 0; j < 4; ++j) {          // jp_local
      float s = 0.f;
#pragma unroll
      for (int rr = 0; rr < 4; ++rr) {
        float xg = acc[j * 4 + rr] + bias;
        s += 0.5f * xg * (1.f + erff(xg * 0.70710678118654752f));
      }
      s += __shfl_xor(s, 32);              // combine lane-halves (t 0..3 | 4..7)
      if (half == 0)
        Gavg[(gbase + j) * 256 + col] = s * 0.125f;
    }
  }
}

// ---------------- pool = mean_t(tok2) + Gavg @ W2 + b2 (FF2 folded 8x by linearity) ----------------
__global__ void __launch_bounds__(256) k_pool2(const float* __restrict__ Gavg,
                        const bf16* __restrict__ tok2, const float* __restrict__ w2,
                        const float* __restrict__ b2, float* __restrict__ pool) {
  __shared__ __align__(16) float sG[18 * 256];     // 18.4 KB
  __shared__ __align__(16) float sRed[4 * 18 * 64]; // 18.4 KB
  int blk = blockIdx.x;
  int b = blk / 128;
  int rem = blk % 128;
  int ch = rem >> 1, jph = rem & 1;
  int tid = threadIdx.x;
  size_t grow0 = ((size_t)(b * 64 + ch) * 36 + jph * 18) * 256;
  for (int e = tid; e < 1152; e += 256) {          // 18 rows x 64 float4
    int row = e >> 6, c4 = e & 63;
    *(float4*)&sG[row * 256 + c4 * 4] = *(const float4*)&Gavg[grow0 + row * 256 + c4 * 4];
  }
  __syncthreads();
  int kg = tid >> 6, dd = tid & 63;
  float acc[18];
#pragma unroll
  for (int i = 0; i < 18; ++i) acc[i] = 0.f;
  for (int k4 = 0; k4 < 16; ++k4) {
    int k = kg * 64 + k4 * 4;
    float w0 = w2[(k + 0) * 64 + dd];
    float w1 = w2[(k + 1) * 64 + dd];
    float w2v = w2[(k + 2) * 64 + dd];
    float w3 = w2[(k + 3) * 64 + dd];
#pragma unroll
    for (int i = 0; i < 18; ++i) {
      float4 gf = *(const float4*)&sG[i * 256 + k];   // wave-wide broadcast
      acc[i] += gf.x * w0 + gf.y * w1 + gf.z * w2v + gf.w * w3;
    }
  }
#pragma unroll
  for (int i = 0; i < 18; ++i) sRed[(kg * 18 + i) * 64 + dd] = acc[i];
  __syncthreads();
  for (int o = tid; o < 1152; o += 256) {
    int jp18 = o >> 6, d2 = o & 63;
    float gsum = sRed[(0 * 18 + jp18) * 64 + d2] + sRed[(1 * 18 + jp18) * 64 + d2]
               + sRed[(2 * 18 + jp18) * 64 + d2] + sRed[(3 * 18 + jp18) * 64 + d2];
    int p = (jph * 18 + jp18) * 64 + d2;
    size_t tbase = (size_t)b * 1179648 + (size_t)ch * 18432 + p;
    float ts = 0.f;
#pragma unroll
    for (int t = 0; t < 8; ++t) ts += bf2f(tok2[tbase + t * 2304]);
    pool[((size_t)(b * 64 + ch)) * HW + p] = ts * 0.125f + gsum + b2[d2];
  }
}

// ---------------- conv(5x5,pad2) + global-avg-pool folded ----------------
__global__ void __launch_bounds__(256) k_convsum(const float* __restrict__ pool,
                                                 const float* __restrict__ x,
                                                 const float* __restrict__ w,
                                                 float* __restrict__ partial) {
  int blk = blockIdx.x;          // b*65 + ch
  int b = blk / 65, ch = blk % 65;
  int tid = threadIdx.x;
  __shared__ float cls[25];
  __shared__ float red[256];
  if (tid < 25) {
    int ry = tid / 5, rx = tid % 5;
    int kh0 = (ry <= 2) ? 0 : (ry == 3 ? 1 : 2);
    int kh1 = (ry >= 2) ? 4 : (ry == 1 ? 3 : 2);
    int kw0 = (rx <= 2) ? 0 : (rx == 3 ? 1 : 2);
    int kw1 = (rx >= 2) ? 4 : (rx == 1 ? 3 : 2);
    float s = 0.f;
    for (int kh = kh0; kh <= kh1; ++kh)
      for (int kw = kw0; kw <= kw1; ++kw)
        s += w[ch * 25 + kh * 5 + kw];
    cls[tid] = s;
  }
  __syncthreads();
  const float* pc = (ch < 64) ? (pool + ((size_t)(b * 64 + ch)) * HW)
                              : (x + (size_t)b * 3 * S_ + 2 * S_);
  float acc = 0.f;
#pragma unroll
  for (int e = tid; e < HW; e += 256) {
    int iy = e / 48, ix = e % 48;
    int ry = (iy == 0) ? 0 : (iy == 1) ? 1 : (iy <= 45) ? 2 : (iy == 46) ? 3 : 4;
    int rx = (ix == 0) ? 0 : (ix == 1) ? 1 : (ix <= 45) ? 2 : (ix == 46) ? 3 : 4;
    acc += pc[e] * cls[ry * 5 + rx];
  }
  red[tid] = acc;
  __syncthreads();
  for (int s = 128; s; s >>= 1) {
    if (tid < s) red[tid] += red[tid + s];
    __syncthreads();
  }
  if (!tid) partial[blk] = red[0];
}

// ---------------- reduce 65 channel sums per b + readout ----------------
__global__ void k_final(const float* __restrict__ partial, const float* __restrict__ tgt_b,
                        const float* __restrict__ rd_w, const float* __restrict__ rd_b,
                        float* __restrict__ out) {
  int b = blockIdx.x;
  int lane = threadIdx.x;
  float s = (lane < 65) ? partial[b * 65 + lane] : 0.f;
  for (int off = 32; off; off >>= 1) s += __shfl_down(s, off, 64);
  __shared__ float r2;
  if (lane == 64) r2 = s;
  __syncthreads();
  if (!lane) {
    float tot = s + r2;
    float mean = tot / 2304.f + tgt_b[0];
    out[b] = mean * rd_w[0] + rd_b[0];
  }
}

extern "C" void kernel_launch(void* const* d_in, const int* in_sizes, int n_in,
                              void* d_out, int out_size, void* d_ws, size_t ws_size,
                              hipStream_t stream) {
  const float* x     = (const float*)d_in[0];
  const float* pre_w = (const float*)d_in[1];
  const float* pre_b = (const float*)d_in[2];
  const float* ln1_g = (const float*)d_in[3];
  const float* ln1_b = (const float*)d_in[4];
  const float* wq    = (const float*)d_in[5];
  const float* wk    = (const float*)d_in[6];
  const float* wv    = (const float*)d_in[7];
  const float* wo    = (const float*)d_in[8];
  const float* bo    = (const float*)d_in[9];
  const float* proj  = (const float*)d_in[10];
  const float* ln2_g = (const float*)d_in[11];
  const float* ln2_b = (const float*)d_in[12];
  const float* ff_w1 = (const float*)d_in[13];
  const float* ff_b1 = (const float*)d_in[14];
  const float* ff_w2 = (const float*)d_in[15];
  const float* ff_b2 = (const float*)d_in[16];
  const float* tgt_w = (const float*)d_in[17];
  const float* tgt_b = (const float*)d_in[18];
  const float* rd_w  = (const float*)d_in[19];
  const float* rd_b  = (const float*)d_in[20];
  float* out = (float*)d_out;

  float* ws = (float*)d_ws;
  // 0 tok(bf16) | 1 v(bf16) | 2 q(bf16) -> Gavg+pool | 3 k(bf16) -> attnb(bf16)
  // 4 h2(bf16) | 6 qpb | 7 kpb | 8 ckv(f32) -> tok2(bf16) | smalls @ 9*BSD+147456
  bf16*  tok   = (bf16*)ws;
  bf16*  v     = (bf16*)(ws + (size_t)BSD);
  bf16*  q     = (bf16*)(ws + 2 * (size_t)BSD);
  float* Gavg  = ws + 2 * (size_t)BSD;          // q dead after featcsfin
  float* pool  = Gavg + 1179648;                // 294912 floats
  bf16*  k     = (bf16*)(ws + 3 * (size_t)BSD); // live until featcsfin
  bf16*  h2    = (bf16*)(ws + 4 * (size_t)BSD);
  bf16*  qpb   = (bf16*)(ws + 6 * (size_t)BSD); // BHSM bf16
  bf16*  kpb   = (bf16*)(ws + 7 * (size_t)BSD); // BHSM bf16
  float* ckv   = ws + 8 * (size_t)BSD;          // 2506752 floats; dead after k_attn
  bf16*  tok2  = (bf16*)(ws + 8 * (size_t)BSD); // written by k_wo_ln (ckv dead)
  bf16*  attnb = k;                             // k dead after featcsfin
  float* smalls = ws + 9 * (size_t)BSD + 147456;
  float* gmax  = smalls;                        // 64 slots x 32-float stride = 2048
  float* partial = smalls + 2048;               // 130 (256 reserved)
  short* wqT   = (short*)(smalls + 2304);       // 4096 shorts = 2048 floats
  short* wkT   = (short*)(smalls + 4352);
  short* wvT   = (short*)(smalls + 6400);
  short* woT   = (short*)(smalls + 8448);
  short* w1T   = (short*)(smalls + 10496);      // 16384 shorts = 8192 floats
  short* projb = (short*)(smalls + 18688);      // 512 shorts = 256 floats

  k_prep<<<dim3(64), dim3(256), 0, stream>>>(wq, wk, wv, wo, ff_w1, proj,
                                             wqT, wkT, wvT, woT, w1T, projb, gmax);
  k_preqkv<<<dim3(BS / 32), dim3(256), 0, stream>>>(x, pre_w, pre_b, ln1_g, ln1_b,
                                                    wqT, wkT, wvT, projb, tok, q, k, v, gmax);
  k_featcsfin<<<dim3(BH * NC + BHS / 128), dim3(256), 0, stream>>>(gmax, q, k, v, projb,
                                                                   qpb, kpb, ckv);
  k_scan<<<dim3(BH * (STATE / SCB)), dim3(256), 0, stream>>>(ckv);
  k_attn<<<dim3(BH * NC / 4), dim3(256), 0, stream>>>(qpb, kpb, v, ckv, attnb);
  k_wo_ln<<<dim3(BS / 32), dim3(128), 0, stream>>>(attnb, woT, bo, tok, ln2_g, ln2_b, tok2, h2);
  k_ffg<<<dim3(B_ * 64 * 9), dim3(256), 0, stream>>>(h2, w1T, ff_b1, Gavg);
  k_pool2<<<dim3(B_ * 64 * 2), dim3(256), 0, stream>>>(Gavg, tok2, ff_w2, ff_b2, pool);
  k_convsum<<<dim3(B_ * 65), dim3(256), 0, stream>>>(pool, x, tgt_w, partial);
  k_final<<<dim3(B_), dim3(128), 0, stream>>>(partial, tgt_b, rd_w, rd_b, out);
}

// Round 6
// 195.280 us; speedup vs baseline: 1.0587x; 1.0587x over previous
//
#include <hip/hip_runtime.h>
#include <hip/hip_bf16.h>
#include <math.h>

typedef __hip_bfloat16 bf16;
typedef __attribute__((ext_vector_type(8))) short short8;
typedef __attribute__((ext_vector_type(16))) float floatx16;

// Problem constants
constexpr int B_   = 2;
constexpr int T_   = 8;
constexpr int HW   = 48 * 48;          // 2304
constexpr int S_   = T_ * HW;          // 18432
constexpr int D_   = 64;
constexpr int NH   = 4;
constexpr int DH   = 16;
constexpr int M_   = 32;
constexpr int BS   = B_ * S_;          // 36864 tokens
constexpr int BSD  = BS * D_;          // 2359296
constexpr int BH   = B_ * NH;          // 8 sequences
constexpr int BHS  = BH * S_;          // 147456 rows
constexpr int CHUNK = 32;
constexpr int NC   = S_ / CHUNK;       // 576 chunks per sequence
constexpr int STATE = M_ * DH + M_;    // 544 floats of scan state
constexpr int GSLOTS = 64;             // gmax atomic slots
constexpr int GSTRIDE = 32;            // floats between slots (128 B = own cache line)
constexpr int SCB = 16;                // scan: state-elems per block
constexpr int SRG = 16;                // scan: runs per (bh, c)
constexpr int SRUN = NC / SRG;         // 36 chunks per run
constexpr float DN = 0.5f;                         // 16^-0.25
constexpr float RATIO = 0.17677669529663687f;      // 32^-0.5

__device__ __forceinline__ unsigned short f2bf(float f) {
  bf16 h = __float2bfloat16(f);
  return *reinterpret_cast<unsigned short*>(&h);
}
__device__ __forceinline__ float bf2f(bf16 v) { return __bfloat162float(v); }
__device__ __forceinline__ float bfs2f(short s) {
  return __uint_as_float(((unsigned)(unsigned short)s) << 16);
}
__device__ __forceinline__ void atomicMaxFloat(float* addr, float val) {
  if (val >= 0.f) atomicMax((int*)addr, __float_as_int(val));
  else atomicMin((unsigned int*)addr, __float_as_uint(val));
}

// ---- prep: bf16 weight conversion (transposed so MFMA B-frags are contiguous short8)
// ---- + gmax slot init. Bitwise-identical values to per-kernel f2bf conversion.
__global__ void __launch_bounds__(256) k_prep(const float* __restrict__ wq,
        const float* __restrict__ wk, const float* __restrict__ wv,
        const float* __restrict__ wo, const float* __restrict__ w1,
        const float* __restrict__ proj,
        short* __restrict__ wqT, short* __restrict__ wkT, short* __restrict__ wvT,
        short* __restrict__ woT, short* __restrict__ w1T, short* __restrict__ projb,
        float* __restrict__ gmax) {
  int tid = blockIdx.x * 256 + threadIdx.x;      // 64 blocks x 256 = 16384
  if (tid < GSLOTS) ((unsigned*)gmax)[tid * GSTRIDE] = 0xff800000u;   // -inf seed
  if (tid < 512) projb[tid] = (short)f2bf(proj[tid]);                 // [32][16] row-major
  if (tid < 4096) {
    int c = tid >> 6, r = tid & 63;              // T[c][r] = w[r][c]
    wqT[tid] = (short)f2bf(wq[r * 64 + c]);
    wkT[tid] = (short)f2bf(wk[r * 64 + c]);
    wvT[tid] = (short)f2bf(wv[r * 64 + c]);
    woT[tid] = (short)f2bf(wo[r * 64 + c]);
  }
  {
    int c = tid >> 6, r = tid & 63;              // w1: [64][256] -> T[256][64]
    w1T[tid] = (short)f2bf(w1[r * 256 + c]);
  }
}

// ---- fused: conv3d(1x1x1)+softplus+LN1 (LDS) + QKV MFMA + k-dash global max (C-lite).
// ---- h never hits HBM; q,k stored PRE-SCALED by DN (exact exponent shift).
__global__ void __launch_bounds__(256) k_preqkv(const float* __restrict__ x,
                      const float* __restrict__ pw, const float* __restrict__ pb,
                      const float* __restrict__ g, const float* __restrict__ bb,
                      const short* __restrict__ wqT, const short* __restrict__ wkT,
                      const short* __restrict__ wvT, const short* __restrict__ projb,
                      bf16* __restrict__ tok, bf16* __restrict__ q,
                      bf16* __restrict__ k, bf16* __restrict__ v,
                      float* __restrict__ gmax) {
  __shared__ __align__(16) short sh[32 * 64];     // LN1 out, XOR-swizzled 16B chunks
  __shared__ __align__(16) short sk[32 * 64];     // (k*DN) bf16, [token][d], byte-swizzled
  int tid = threadIdx.x;
  int tbase = blockIdx.x * 32;

  // ---- phase A: 32 tokens x 64 channels; each thread owns 8 consecutive values
  {
    size_t f0 = (size_t)tbase * 64;
    int b = (int)(f0 / ((size_t)D_ * S_));
    int rem = (int)(f0 % ((size_t)D_ * S_));
    int d = rem / S_;                    // whole block lies in one (b,d) plane
    int pos0 = rem % S_;
    float w0 = pw[d * 3 + 0], w1 = pw[d * 3 + 1], w2 = pw[d * 3 + 2], pbd = pb[d];
    const float* xb = x + ((size_t)b * 3) * S_ + pos0 + tid * 8;
    float4 x0a = *(const float4*)(xb);
    float4 x0b = *(const float4*)(xb + 4);
    float4 x1a = *(const float4*)(xb + S_);
    float4 x1b = *(const float4*)(xb + S_ + 4);
    float4 x2a = *(const float4*)(xb + 2 * S_);
    float4 x2b = *(const float4*)(xb + 2 * S_ + 4);
    float xf0[8] = {x0a.x, x0a.y, x0a.z, x0a.w, x0b.x, x0b.y, x0b.z, x0b.w};
    float xf1[8] = {x1a.x, x1a.y, x1a.z, x1a.w, x1b.x, x1b.y, x1b.z, x1b.w};
    float xf2[8] = {x2a.x, x2a.y, x2a.z, x2a.w, x2b.x, x2b.y, x2b.z, x2b.w};
    float t[8];
    short8 tv;
#pragma unroll
    for (int j = 0; j < 8; ++j) {
      float a = xf0[j] * w0 + xf1[j] * w1 + xf2[j] * w2 + pbd;
      t[j] = fmaxf(a, 0.f) + log1pf(expf(-fabsf(a)));   // softplus
      tv[j] = (short)f2bf(t[j]);
    }
    *(short8*)(tok + f0 + (size_t)tid * 8) = tv;
    float s1 = 0.f, s2 = 0.f;
#pragma unroll
    for (int j = 0; j < 8; ++j) { s1 += t[j]; s2 += t[j] * t[j]; }
#pragma unroll
    for (int off = 4; off; off >>= 1) {       // LN reduce over 8 lanes = 64 channels
      s1 += __shfl_xor(s1, off, 8);
      s2 += __shfl_xor(s2, off, 8);
    }
    float mu = s1 * (1.f / 64.f);
    float var = s2 * (1.f / 64.f) - mu * mu;
    float rs = rsqrtf(var + 1e-5f);
    int tt = tid >> 3, j8 = tid & 7;
    short8 hv;
#pragma unroll
    for (int j = 0; j < 8; ++j) {
      int c = j8 * 8 + j;
      hv[j] = (short)f2bf((t[j] - mu) * rs * g[c] + bb[c]);
    }
    *(short8*)&sh[tt * 64 + ((j8 ^ (tt & 7)) * 8)] = hv;   // XOR-swizzled 16B chunk
  }
  __syncthreads();

  int w = tid >> 6;
  int L = tid & 63;
  int half = L >> 5;
  int n = L & 31;

  // ---- phase B: waves {0,1,2} = {q,k,v} MFMA; bf16 transposed weights, short8 frags
  if (w < 3) {
    const short* wmT = (w == 0) ? wqT : (w == 1) ? wkT : wvT;
    bf16* outm = (w == 0) ? q : (w == 1) ? k : v;

    short8 a[4];
#pragma unroll
    for (int c = 0; c < 4; ++c)
      a[c] = *(const short8*)&sh[n * 64 + (((c * 2 + half) ^ (n & 7)) * 8)];
#pragma unroll
    for (int ct = 0; ct < 2; ++ct) {
      int col = ct * 32 + n;
      short8 bfrag[4];
#pragma unroll
      for (int c = 0; c < 4; ++c)
        bfrag[c] = *(const short8*)&wmT[col * 64 + c * 16 + half * 8];
      floatx16 acc;
#pragma unroll
      for (int i = 0; i < 16; ++i) acc[i] = 0.f;
      acc = __builtin_amdgcn_mfma_f32_32x32x16_bf16(a[0], bfrag[0], acc, 0, 0, 0);
      acc = __builtin_amdgcn_mfma_f32_32x32x16_bf16(a[1], bfrag[1], acc, 0, 0, 0);
      acc = __builtin_amdgcn_mfma_f32_32x32x16_bf16(a[2], bfrag[2], acc, 0, 0, 0);
      acc = __builtin_amdgcn_mfma_f32_32x32x16_bf16(a[3], bfrag[3], acc, 0, 0, 0);
      int head = col >> 4, di = col & 15;
#pragma unroll
      for (int r = 0; r < 16; ++r) {
        int row = (r & 3) + 8 * (r >> 2) + 4 * half;
        int token = tbase + row;
        int b = token / S_, s = token % S_;
        unsigned short us = f2bf(acc[r]);
        if (w == 2) {
          outm[((size_t)(b * NH + head) * S_ + s) * DH + di] = *(bf16*)&us;
        } else {
          unsigned short usd = f2bf(bfs2f((short)us) * DN);   // exact x0.5 round-trip
          outm[((size_t)(b * NH + head) * S_ + s) * DH + di] = *(bf16*)&usd;
          if (w == 1)
            *(short*)((char*)sk + row * 128 + ((col * 2) ^ ((row & 7) << 4))) = (short)usd;
        }
      }
    }
  }
  __syncthreads();

  // ---- phase C-lite: wave w = head w. One Pk MFMA, raw-dash max, spread atomic.
  {
    short8 ak;
    short8 bp = *(const short8*)&projb[n * 16 + half * 8];    // B[d][m=n]
    int roff = n * 128 + ((w * 32 + half * 16) ^ ((n & 7) << 4));
    ak = *(const short8*)((const char*)sk + roff);
    floatx16 Pk;
#pragma unroll
    for (int i = 0; i < 16; ++i) Pk[i] = 0.f;
    Pk = __builtin_amdgcn_mfma_f32_32x32x16_bf16(ak, bp, Pk, 0, 0, 0);
    float bmax = -3.4e38f;
#pragma unroll
    for (int r = 0; r < 16; ++r) bmax = fmaxf(bmax, Pk[r]);
    for (int off = 32; off; off >>= 1) bmax = fmaxf(bmax, __shfl_xor(bmax, off));
    if (L == 0)
      atomicMaxFloat(&gmax[((blockIdx.x * 4 + w) & (GSLOTS - 1)) * GSTRIDE], bmax);
  }
}

// ---- one dispatch, two independent block-ranges running CONCURRENTLY:
// ----   blk < BH*NC/4 (1152) : csfin, 1 WAVE PER CHUNK, all-MFMA, no barriers
// ----   blk >= BH*NC/4       : feat  (qp feature map, reads q only)
// ---- q,k arrive PRE-SCALED by DN.
__global__ void __launch_bounds__(256) k_featcsfin(const float* __restrict__ gmax,
                      const bf16* __restrict__ q, const bf16* __restrict__ k,
                      const bf16* __restrict__ v, const short* __restrict__ projb,
                      bf16* __restrict__ qpb, bf16* __restrict__ kpb,
                      float* __restrict__ ckv) {
  __shared__ __align__(16) float sKp[4][CHUNK * 32];   // per-wave Kp tile (16 KB)
  int tid = threadIdx.x;
  int w = tid >> 6, L = tid & 63, half = L >> 5, n = L & 31;
  short8 bp = *(const short8*)&projb[n * 16 + half * 8];     // B[d][m=n]

  if (blockIdx.x >= BH * NC / 4) {
    // ---------------- feat: qp bf16 out; 128 rows per block ----------------
    int fblk = blockIdx.x - BH * NC / 4;
    int rowbase = fblk * 128 + w * 32;
    short8 aq = *(const short8*)(q + (size_t)(rowbase + n) * 16 + half * 8);
    float dq = 0.f;
#pragma unroll
    for (int j = 0; j < 8; ++j) { float f = bfs2f(aq[j]); dq += f * f; }
    dq += __shfl_xor(dq, 32);
    dq *= 0.5f;
    floatx16 Pq;
#pragma unroll
    for (int i = 0; i < 16; ++i) Pq[i] = 0.f;
    Pq = __builtin_amdgcn_mfma_f32_32x32x16_bf16(aq, bp, Pq, 0, 0, 0);
#pragma unroll
    for (int r = 0; r < 16; ++r) {
      int i = (r & 3) + 8 * (r >> 2) + 4 * half;
      float mx = Pq[r];
      for (int off = 16; off; off >>= 1) mx = fmaxf(mx, __shfl_xor(mx, off, 32));
      float dqi = __shfl(dq, i, 64);          // row i's dq lives on lane i (<32)
      float val = RATIO * (expf(Pq[r] - dqi - mx) + 1e-4f);
      qpb[(size_t)(rowbase + i) * 32 + n] = __float2bfloat16(val);
    }
    return;
  }

  // ---------------- csfin: wave w owns chunk blockIdx.x*4 + w ----------------
  int chunk = blockIdx.x * 4 + w;
  int bh = chunk / NC, c = chunk % NC;
  int base = bh * S_ + c * CHUNK;
  float gm = gmax[L * GSTRIDE];             // 64 slots -> wave-reduce max
  for (int off = 32; off; off >>= 1) gm = fmaxf(gm, __shfl_xor(gm, off));
  short8 ak = *(const short8*)(k + (size_t)(base + n) * 16 + half * 8);
  float dk = 0.f;
#pragma unroll
  for (int j = 0; j < 8; ++j) { float f = bfs2f(ak[j]); dk += f * f; }
  dk += __shfl_xor(dk, 32);
  dk *= 0.5f;
  floatx16 Pk;
#pragma unroll
  for (int i = 0; i < 16; ++i) Pk[i] = 0.f;
  Pk = __builtin_amdgcn_mfma_f32_32x32x16_bf16(ak, bp, Pk, 0, 0, 0);
  float* sp = &sKp[w][0];
#pragma unroll
  for (int r = 0; r < 16; ++r) {
    int i = (r & 3) + 8 * (r >> 2) + 4 * half;
    float dgi = __shfl(dk, i, 64);
    sp[i * 32 + n] = RATIO * (expf(Pk[r] - dgi - gm) + 1e-4f);
  }
  // A-frags: Kp^T[m=n][t], from own wave's LDS (no barrier needed)
  short8 a1, a2;
#pragma unroll
  for (int j = 0; j < 8; ++j) {
    a1[j] = (short)f2bf(sp[(half * 8 + j) * 32 + n]);
    a2[j] = (short)f2bf(sp[(16 + half * 8 + j) * 32 + n]);
  }
  // B-frags: V with ones column at col 16 (gives K column-sums az for free)
  const unsigned short one_bf = f2bf(1.f);
  short8 vb1, vb2;
#pragma unroll
  for (int j = 0; j < 8; ++j) {
    int t1 = half * 8 + j, t2 = 16 + half * 8 + j;
    vb1[j] = (n < 16) ? *(const short*)(v + (size_t)(base + t1) * 16 + n)
                      : (short)(n == 16 ? one_bf : 0);
    vb2[j] = (n < 16) ? *(const short*)(v + (size_t)(base + t2) * 16 + n)
                      : (short)(n == 16 ? one_bf : 0);
  }
  floatx16 O;
#pragma unroll
  for (int i = 0; i < 16; ++i) O[i] = 0.f;
  O = __builtin_amdgcn_mfma_f32_32x32x16_bf16(a1, vb1, O, 0, 0, 0);
  O = __builtin_amdgcn_mfma_f32_32x32x16_bf16(a2, vb2, O, 0, 0, 0);
  float* outp = ckv + (size_t)chunk * STATE;
#pragma unroll
  for (int r = 0; r < 16; ++r) {
    int m = (r & 3) + 8 * (r >> 2) + 4 * half;
    if (n < 16) outp[m * 16 + n] = O[r];
    else if (n == 16) outp[512 + m] = O[r];
  }
  // kpb store: lane handles half a row (16 bf16 = 32 B), fully coalesced per wave
  {
    int row = L >> 1, c8 = (L & 1) * 16;
    const float* srcp = sp + row * 32 + c8;
    uint4 u0, u1;
    u0.x = (unsigned)f2bf(srcp[0])  | ((unsigned)f2bf(srcp[1])  << 16);
    u0.y = (unsigned)f2bf(srcp[2])  | ((unsigned)f2bf(srcp[3])  << 16);
    u0.z = (unsigned)f2bf(srcp[4])  | ((unsigned)f2bf(srcp[5])  << 16);
    u0.w = (unsigned)f2bf(srcp[6])  | ((unsigned)f2bf(srcp[7])  << 16);
    u1.x = (unsigned)f2bf(srcp[8])  | ((unsigned)f2bf(srcp[9])  << 16);
    u1.y = (unsigned)f2bf(srcp[10]) | ((unsigned)f2bf(srcp[11]) << 16);
    u1.z = (unsigned)f2bf(srcp[12]) | ((unsigned)f2bf(srcp[13]) << 16);
    u1.w = (unsigned)f2bf(srcp[14]) | ((unsigned)f2bf(srcp[15]) << 16);
    *(uint4*)&kpb[(size_t)(base + row) * 32 + c8] = u0;
    *(uint4*)&kpb[(size_t)(base + row) * 32 + c8 + 8] = u1;
  }
}

// ---- single-kernel segmented exclusive scan: 16 runs of 36 chunks, LDS run-prefix ----
__global__ void __launch_bounds__(256) k_scan(float* __restrict__ ckv) {
  __shared__ float sS[SRG][SCB];
  int blk = blockIdx.x;                      // BH * (STATE/SCB) = 8*34 = 272
  int bh = blk / (STATE / SCB);
  int c0 = (blk % (STATE / SCB)) * SCB;
  int cl = threadIdx.x & (SCB - 1);
  int rg = threadIdx.x >> 4;
  int c = c0 + cl;
  size_t base = ((size_t)bh * NC + rg * SRUN) * STATE + c;
  float s = 0.f;
#pragma unroll 6
  for (int i = 0; i < SRUN; ++i) s += ckv[base + (size_t)i * STATE];
  sS[rg][cl] = s;
  __syncthreads();
  float run = 0.f;
  for (int r = 0; r < rg; ++r) run += sS[r][cl];
  for (int i0 = 0; i0 < SRUN; i0 += 6) {
    float tb[6];
#pragma unroll
    for (int j = 0; j < 6; ++j) tb[j] = ckv[base + (size_t)(i0 + j) * STATE];
#pragma unroll
    for (int j = 0; j < 6; ++j) {
      ckv[base + (size_t)(i0 + j) * STATE] = run;
      run += tb[j];
    }
  }
}

// ---------------- within-chunk causal attention via MFMA (CHUNK=32; 4 chunks/block) ----------------
__global__ void __launch_bounds__(256) k_attn(const bf16* __restrict__ qpb,
                                              const bf16* __restrict__ kpb,
                                              const bf16* __restrict__ v,
                                              const float* __restrict__ ckv,
                                              bf16* __restrict__ attn) {
  __shared__ __align__(16) float sP[4][32 * 33 + 4];
  int tid = threadIdx.x;
  int w = tid >> 6;                 // wave -> chunk
  int L = tid & 63;
  int half = L >> 5;
  int n = L & 31;
  int chunk = blockIdx.x * 4 + w;
  int bh = chunk / NC, c = chunk % NC;
  int base = bh * S_ + c * CHUNK;

  short8 a1 = *(const short8*)(qpb + (size_t)(base + n) * 32 + half * 8);
  short8 a2 = *(const short8*)(qpb + (size_t)(base + n) * 32 + 16 + half * 8);
  short8 b1 = *(const short8*)(kpb + (size_t)(base + n) * 32 + half * 8);
  short8 b2 = *(const short8*)(kpb + (size_t)(base + n) * 32 + 16 + half * 8);

  floatx16 P;
#pragma unroll
  for (int i = 0; i < 16; ++i) P[i] = 0.f;
  P = __builtin_amdgcn_mfma_f32_32x32x16_bf16(a1, b1, P, 0, 0, 0);
  P = __builtin_amdgcn_mfma_f32_32x32x16_bf16(a2, b2, P, 0, 0, 0);

  float* sp = &sP[w][0];
#pragma unroll
  for (int r = 0; r < 16; ++r) {
    int i = (r & 3) + 8 * (r >> 2) + 4 * half;
    sp[i * 33 + n] = (n <= i) ? P[r] : 0.f;
  }
  __syncthreads();
  short8 pa1, pa2;
#pragma unroll
  for (int j = 0; j < 8; ++j) {
    pa1[j] = (short)f2bf(sp[n * 33 + half * 8 + j]);
    pa2[j] = (short)f2bf(sp[n * 33 + 16 + half * 8 + j]);
  }

  const float* cs = ckv + (size_t)chunk * STATE;
  const unsigned short one_bf = f2bf(1.f);
  short8 vb1, vb2, sb1, sb2;
#pragma unroll
  for (int j = 0; j < 8; ++j) {
    int t1 = half * 8 + j, t2 = 16 + half * 8 + j;
    vb1[j] = (n < 16) ? *(const short*)(v + (size_t)(base + t1) * 16 + n)
                      : (short)(n == 16 ? one_bf : 0);
    vb2[j] = (n < 16) ? *(const short*)(v + (size_t)(base + t2) * 16 + n)
                      : (short)(n == 16 ? one_bf : 0);
    float y1 = (n < 16) ? cs[t1 * 16 + n] : (n == 16 ? cs[512 + t1] : 0.f);
    float y2 = (n < 16) ? cs[t2 * 16 + n] : (n == 16 ? cs[512 + t2] : 0.f);
    sb1[j] = (short)f2bf(y1);
    sb2[j] = (short)f2bf(y2);
  }

  floatx16 O;
#pragma unroll
  for (int i = 0; i < 16; ++i) O[i] = 0.f;
  O = __builtin_amdgcn_mfma_f32_32x32x16_bf16(pa1, vb1, O, 0, 0, 0);
  O = __builtin_amdgcn_mfma_f32_32x32x16_bf16(pa2, vb2, O, 0, 0, 0);
  O = __builtin_amdgcn_mfma_f32_32x32x16_bf16(a1, sb1, O, 0, 0, 0);
  O = __builtin_amdgcn_mfma_f32_32x32x16_bf16(a2, sb2, O, 0, 0, 0);

  int srcl = 16 + 32 * half;
  float res[16];
#pragma unroll
  for (int r = 0; r < 16; ++r) {
    float den = __shfl(O[r], srcl, 64);
    res[r] = O[r] / den;
  }
  if (n < 16) {
    int b = bh >> 2, head = bh & 3;
#pragma unroll
    for (int r = 0; r < 16; ++r) {
      int i = (r & 3) + 8 * (r >> 2) + 4 * half;
      attn[((size_t)(b * S_ + c * CHUNK + i)) * 64 + head * 16 + n] = __float2bfloat16(res[r]);
    }
  }
}

// ---------------- attn(bf16) @ wo + bo + residual(bf16) + LayerNorm2; tok2 bf16, h2 bf16 ----------
__global__ void __launch_bounds__(128) k_wo_ln(const bf16* __restrict__ attn,
                        const short* __restrict__ woT, const float* __restrict__ bo,
                        const bf16* __restrict__ tok, const float* __restrict__ g,
                        const float* __restrict__ bb,
                        bf16* __restrict__ tok2, bf16* __restrict__ h2) {
  __shared__ __align__(16) float sC[32 * 68];
  int tid = threadIdx.x;
  int w = tid >> 6;                 // coltile
  int L = tid & 63;
  int half = L >> 5;
  int n = L & 31;
  int tbase = blockIdx.x * 32;

  short8 a[4];
  {
    const bf16* arow = attn + (size_t)(tbase + n) * 64 + half * 8;
#pragma unroll
    for (int c = 0; c < 4; ++c) a[c] = *(const short8*)(arow + c * 16);
  }
  int col = w * 32 + n;
  short8 bfrag[4];
#pragma unroll
  for (int c = 0; c < 4; ++c)
    bfrag[c] = *(const short8*)&woT[col * 64 + c * 16 + half * 8];
  floatx16 acc;
#pragma unroll
  for (int i = 0; i < 16; ++i) acc[i] = 0.f;
  acc = __builtin_amdgcn_mfma_f32_32x32x16_bf16(a[0], bfrag[0], acc, 0, 0, 0);
  acc = __builtin_amdgcn_mfma_f32_32x32x16_bf16(a[1], bfrag[1], acc, 0, 0, 0);
  acc = __builtin_amdgcn_mfma_f32_32x32x16_bf16(a[2], bfrag[2], acc, 0, 0, 0);
  acc = __builtin_amdgcn_mfma_f32_32x32x16_bf16(a[3], bfrag[3], acc, 0, 0, 0);
  float bias = bo[col];
#pragma unroll
  for (int r = 0; r < 16; ++r) {
    int row = (r & 3) + 8 * (r >> 2) + 4 * half;
    sC[row * 68 + col] = acc[r] + bf2f(tok[(size_t)(tbase + row) * 64 + col]) + bias;
  }
  __syncthreads();
  int tg = tid >> 5, cg = tid & 31;
  int c0 = cg * 2, c1 = c0 + 1;
  float g0 = g[c0], g1 = g[c1], be0 = bb[c0], be1 = bb[c1];
#pragma unroll
  for (int i = 0; i < 8; ++i) {
    int lrow = tg * 8 + i;
    int token = tbase + lrow;
    float t0 = sC[lrow * 68 + c0];
    float t1 = sC[lrow * 68 + c1];
    float s1 = t0 + t1, s2 = t0 * t0 + t1 * t1;
    for (int off = 16; off; off >>= 1) {
      s1 += __shfl_xor(s1, off, 32);
      s2 += __shfl_xor(s2, off, 32);
    }
    float mu = s1 * (1.f / 64.f);
    float var = s2 * (1.f / 64.f) - mu * mu;
    float rs = rsqrtf(var + 1e-5f);
    tok2[token * 64 + c0] = __float2bfloat16(t0);
    tok2[token * 64 + c1] = __float2bfloat16(t1);
    h2[token * 64 + c0] = __float2bfloat16((t0 - mu) * rs * g0 + be0);
    h2[token * 64 + c1] = __float2bfloat16((t1 - mu) * rs * g1 + be1);
  }
}

// ---------------- FF1 + Gavg fused via MFMA (h2 bf16 in, bf16 transposed w1) ----------------
__global__ void __launch_bounds__(256) k_ffg(const bf16* __restrict__ h2,
                                             const short* __restrict__ w1T,
                                             const float* __restrict__ b1,
                                             float* __restrict__ Gavg) {
  int tid = threadIdx.x;
  int w = tid >> 6;
  int L = tid & 63;
  int half = L >> 5;
  int n = L & 31;
  int blk = blockIdx.x;                 // B*64*9 = 1152
  int b = blk / 576;
  int rem = blk % 576;
  int ch = rem / 9;
  int jp0 = (rem % 9) * 4;
  int token_n = b * 18432 + ch * 288 + (n & 7) * 36 + jp0 + (n >> 3);

  short8 a[4];
  {
    const bf16* hrow = h2 + (size_t)token_n * 64 + half * 8;
#pragma unroll
    for (int c = 0; c < 4; ++c) a[c] = *(const short8*)(hrow + c * 16);
  }
  size_t gbase = ((size_t)(b * 64 + ch) * 36 + jp0);
#pragma unroll
  for (int ct = 0; ct < 2; ++ct) {
    int col = w * 64 + ct * 32 + n;
    short8 bfrag[4];
#pragma unroll
    for (int c = 0; c < 4; ++c)
      bfrag[c] = *(const short8*)&w1T[col * 64 + c * 16 + half * 8];
    floatx16 acc;
#pragma unroll
    for (int i = 0; i < 16; ++i) acc[i] = 0.f;
    acc = __builtin_amdgcn_mfma_f32_32x32x16_bf16(a[0], bfrag[0], acc, 0, 0, 0);
    acc = __builtin_amdgcn_mfma_f32_32x32x16_bf16(a[1], bfrag[1], acc, 0, 0, 0);
    acc = __builtin_amdgcn_mfma_f32_32x32x16_bf16(a[2], bfrag[2], acc, 0, 0, 0);
    acc = __builtin_amdgcn_mfma_f32_32x32x16_bf16(a[3], bfrag[3], acc, 0, 0, 0);
    float bias = b1[col];
#pragma unroll
    for (int j = 0; j < 4; ++j) {          // jp_local
      float s = 0.f;
#pragma unroll
      for (int rr = 0; rr < 4; ++rr) {
        float xg = acc[j * 4 + rr] + bias;
        s += 0.5f * xg * (1.f + erff(xg * 0.70710678118654752f));
      }
      s += __shfl_xor(s, 32);              // combine lane-halves (t 0..3 | 4..7)
      if (half == 0)
        Gavg[(gbase + j) * 256 + col] = s * 0.125f;
    }
  }
}

// ---------------- pool = mean_t(tok2) + Gavg @ W2 + b2 (FF2 folded 8x by linearity) ----------------
__global__ void __launch_bounds__(256) k_pool2(const float* __restrict__ Gavg,
                        const bf16* __restrict__ tok2, const float* __restrict__ w2,
                        const float* __restrict__ b2, float* __restrict__ pool) {
  __shared__ __align__(16) float sG[18 * 256];     // 18.4 KB
  __shared__ __align__(16) float sRed[4 * 18 * 64]; // 18.4 KB
  int blk = blockIdx.x;
  int b = blk / 128;
  int rem = blk % 128;
  int ch = rem >> 1, jph = rem & 1;
  int tid = threadIdx.x;
  size_t grow0 = ((size_t)(b * 64 + ch) * 36 + jph * 18) * 256;
  for (int e = tid; e < 1152; e += 256) {          // 18 rows x 64 float4
    int row = e >> 6, c4 = e & 63;
    *(float4*)&sG[row * 256 + c4 * 4] = *(const float4*)&Gavg[grow0 + row * 256 + c4 * 4];
  }
  __syncthreads();
  int kg = tid >> 6, dd = tid & 63;
  float acc[18];
#pragma unroll
  for (int i = 0; i < 18; ++i) acc[i] = 0.f;
  for (int k4 = 0; k4 < 16; ++k4) {
    int k = kg * 64 + k4 * 4;
    float w0 = w2[(k + 0) * 64 + dd];
    float w1 = w2[(k + 1) * 64 + dd];
    float w2v = w2[(k + 2) * 64 + dd];
    float w3 = w2[(k + 3) * 64 + dd];
#pragma unroll
    for (int i = 0; i < 18; ++i) {
      float4 gf = *(const float4*)&sG[i * 256 + k];   // wave-wide broadcast
      acc[i] += gf.x * w0 + gf.y * w1 + gf.z * w2v + gf.w * w3;
    }
  }
#pragma unroll
  for (int i = 0; i < 18; ++i) sRed[(kg * 18 + i) * 64 + dd] = acc[i];
  __syncthreads();
  for (int o = tid; o < 1152; o += 256) {
    int jp18 = o >> 6, d2 = o & 63;
    float gsum = sRed[(0 * 18 + jp18) * 64 + d2] + sRed[(1 * 18 + jp18) * 64 + d2]
               + sRed[(2 * 18 + jp18) * 64 + d2] + sRed[(3 * 18 + jp18) * 64 + d2];
    int p = (jph * 18 + jp18) * 64 + d2;
    size_t tbase = (size_t)b * 1179648 + (size_t)ch * 18432 + p;
    float ts = 0.f;
#pragma unroll
    for (int t = 0; t < 8; ++t) ts += bf2f(tok2[tbase + t * 2304]);
    pool[((size_t)(b * 64 + ch)) * HW + p] = ts * 0.125f + gsum + b2[d2];
  }
}

// ---------------- conv(5x5,pad2) + global-avg-pool folded ----------------
__global__ void __launch_bounds__(256) k_convsum(const float* __restrict__ pool,
                                                 const float* __restrict__ x,
                                                 const float* __restrict__ w,
                                                 float* __restrict__ partial) {
  int blk = blockIdx.x;          // b*65 + ch
  int b = blk / 65, ch = blk % 65;
  int tid = threadIdx.x;
  __shared__ float cls[25];
  __shared__ float red[256];
  if (tid < 25) {
    int ry = tid / 5, rx = tid % 5;
    int kh0 = (ry <= 2) ? 0 : (ry == 3 ? 1 : 2);
    int kh1 = (ry >= 2) ? 4 : (ry == 1 ? 3 : 2);
    int kw0 = (rx <= 2) ? 0 : (rx == 3 ? 1 : 2);
    int kw1 = (rx >= 2) ? 4 : (rx == 1 ? 3 : 2);
    float s = 0.f;
    for (int kh = kh0; kh <= kh1; ++kh)
      for (int kw = kw0; kw <= kw1; ++kw)
        s += w[ch * 25 + kh * 5 + kw];
    cls[tid] = s;
  }
  __syncthreads();
  const float* pc = (ch < 64) ? (pool + ((size_t)(b * 64 + ch)) * HW)
                              : (x + (size_t)b * 3 * S_ + 2 * S_);
  float acc = 0.f;
#pragma unroll
  for (int e = tid; e < HW; e += 256) {
    int iy = e / 48, ix = e % 48;
    int ry = (iy == 0) ? 0 : (iy == 1) ? 1 : (iy <= 45) ? 2 : (iy == 46) ? 3 : 4;
    int rx = (ix == 0) ? 0 : (ix == 1) ? 1 : (ix <= 45) ? 2 : (ix == 46) ? 3 : 4;
    acc += pc[e] * cls[ry * 5 + rx];
  }
  red[tid] = acc;
  __syncthreads();
  for (int s = 128; s; s >>= 1) {
    if (tid < s) red[tid] += red[tid + s];
    __syncthreads();
  }
  if (!tid) partial[blk] = red[0];
}

// ---------------- reduce 65 channel sums per b + readout ----------------
__global__ void k_final(const float* __restrict__ partial, const float* __restrict__ tgt_b,
                        const float* __restrict__ rd_w, const float* __restrict__ rd_b,
                        float* __restrict__ out) {
  int b = blockIdx.x;
  int lane = threadIdx.x;
  float s = (lane < 65) ? partial[b * 65 + lane] : 0.f;
  for (int off = 32; off; off >>= 1) s += __shfl_down(s, off, 64);
  __shared__ float r2;
  if (lane == 64) r2 = s;
  __syncthreads();
  if (!lane) {
    float tot = s + r2;
    float mean = tot / 2304.f + tgt_b[0];
    out[b] = mean * rd_w[0] + rd_b[0];
  }
}

extern "C" void kernel_launch(void* const* d_in, const int* in_sizes, int n_in,
                              void* d_out, int out_size, void* d_ws, size_t ws_size,
                              hipStream_t stream) {
  const float* x     = (const float*)d_in[0];
  const float* pre_w = (const float*)d_in[1];
  const float* pre_b = (const float*)d_in[2];
  const float* ln1_g = (const float*)d_in[3];
  const float* ln1_b = (const float*)d_in[4];
  const float* wq    = (const float*)d_in[5];
  const float* wk    = (const float*)d_in[6];
  const float* wv    = (const float*)d_in[7];
  const float* wo    = (const float*)d_in[8];
  const float* bo    = (const float*)d_in[9];
  const float* proj  = (const float*)d_in[10];
  const float* ln2_g = (const float*)d_in[11];
  const float* ln2_b = (const float*)d_in[12];
  const float* ff_w1 = (const float*)d_in[13];
  const float* ff_b1 = (const float*)d_in[14];
  const float* ff_w2 = (const float*)d_in[15];
  const float* ff_b2 = (const float*)d_in[16];
  const float* tgt_w = (const float*)d_in[17];
  const float* tgt_b = (const float*)d_in[18];
  const float* rd_w  = (const float*)d_in[19];
  const float* rd_b  = (const float*)d_in[20];
  float* out = (float*)d_out;

  float* ws = (float*)d_ws;
  // 0 tok(bf16) | 1 v(bf16) | 2 q(bf16) -> Gavg+pool | 3 k(bf16) -> attnb(bf16)
  // 4 h2(bf16) | 6 qpb | 7 kpb | 8 ckv(f32) -> tok2(bf16) | smalls @ 9*BSD+147456
  bf16*  tok   = (bf16*)ws;
  bf16*  v     = (bf16*)(ws + (size_t)BSD);
  bf16*  q     = (bf16*)(ws + 2 * (size_t)BSD);
  float* Gavg  = ws + 2 * (size_t)BSD;          // q dead after featcsfin
  float* pool  = Gavg + 1179648;                // 294912 floats
  bf16*  k     = (bf16*)(ws + 3 * (size_t)BSD); // live until featcsfin
  bf16*  h2    = (bf16*)(ws + 4 * (size_t)BSD);
  bf16*  qpb   = (bf16*)(ws + 6 * (size_t)BSD); // BHSM bf16
  bf16*  kpb   = (bf16*)(ws + 7 * (size_t)BSD); // BHSM bf16
  float* ckv   = ws + 8 * (size_t)BSD;          // 2506752 floats; dead after k_attn
  bf16*  tok2  = (bf16*)(ws + 8 * (size_t)BSD); // written by k_wo_ln (ckv dead)
  bf16*  attnb = k;                             // k dead after featcsfin
  float* smalls = ws + 9 * (size_t)BSD + 147456;
  float* gmax  = smalls;                        // 64 slots x 32-float stride = 2048
  float* partial = smalls + 2048;               // 130 (256 reserved)
  short* wqT   = (short*)(smalls + 2304);       // 4096 shorts = 2048 floats
  short* wkT   = (short*)(smalls + 4352);
  short* wvT   = (short*)(smalls + 6400);
  short* woT   = (short*)(smalls + 8448);
  short* w1T   = (short*)(smalls + 10496);      // 16384 shorts = 8192 floats
  short* projb = (short*)(smalls + 18688);      // 512 shorts = 256 floats

  k_prep<<<dim3(64), dim3(256), 0, stream>>>(wq, wk, wv, wo, ff_w1, proj,
                                             wqT, wkT, wvT, woT, w1T, projb, gmax);
  k_preqkv<<<dim3(BS / 32), dim3(256), 0, stream>>>(x, pre_w, pre_b, ln1_g, ln1_b,
                                                    wqT, wkT, wvT, projb, tok, q, k, v, gmax);
  k_featcsfin<<<dim3(BH * NC / 4 + BHS / 128), dim3(256), 0, stream>>>(gmax, q, k, v, projb,
                                                                       qpb, kpb, ckv);
  k_scan<<<dim3(BH * (STATE / SCB)), dim3(256), 0, stream>>>(ckv);
  k_attn<<<dim3(BH * NC / 4), dim3(256), 0, stream>>>(qpb, kpb, v, ckv, attnb);
  k_wo_ln<<<dim3(BS / 32), dim3(128), 0, stream>>>(attnb, woT, bo, tok, ln2_g, ln2_b, tok2, h2);
  k_ffg<<<dim3(B_ * 64 * 9), dim3(256), 0, stream>>>(h2, w1T, ff_b1, Gavg);
  k_pool2<<<dim3(B_ * 64 * 2), dim3(256), 0, stream>>>(Gavg, tok2, ff_w2, ff_b2, pool);
  k_convsum<<<dim3(B_ * 65), dim3(256), 0, stream>>>(pool, x, tgt_w, partial);
  k_final<<<dim3(B_), dim3(128), 0, stream>>>(partial, tgt_b, rd_w, rd_b, out);
}